// Round 5
// baseline (775.218 us; speedup 1.0000x reference)
//
#include <hip/hip_runtime.h>
#include <hip/hip_bf16.h>
#include <math.h>
#include <stdint.h>

// ---------------------------------------------------------------------------
// Transformer block: x + attn(rms(x,g1)) -> x1 ; x1 + ffn(rms(x1,g2))
// B=2 T=2048 D=1024 H=16 Dh=64 FF=4096. All GEMMs bf16 MFMA 16x16x32.
// LDS tiles use XOR-swizzled 16B chunks (chunk j of row r lives at j^(r&7)).
// GEMM K-loop: global->VGPR prefetch + ds_write pipeline (loads for tile k+1
// stay in flight across the barrier; no vmcnt(0) drain per iteration).
// ---------------------------------------------------------------------------

typedef __bf16 v8bf  __attribute__((ext_vector_type(8)));
typedef float  v4f   __attribute__((ext_vector_type(4)));

#define T_SEQ 2048
#define EXP2F(x) __builtin_amdgcn_exp2f(x)  // v_exp_f32 (2^x)

// swizzled fragment read: row R, k-elem offset ko (multiple of 8)
#define FRAG(base, R, ko) \
  (*(const v8bf*)((base) + (R) * 64 + (((((ko) >> 3) ^ ((R) & 7))) << 3)))

__device__ __forceinline__ void async_ld16(const void* g, void* l) {
  __builtin_amdgcn_global_load_lds(
      (const __attribute__((address_space(1))) uint32_t*)g,
      (__attribute__((address_space(3))) uint32_t*)l, 16, 0, 0);
}

// ---------------- 4x weight transpose (Wq,Wk,Wv,Wo) fused ------------------
// out is contiguous [4][1024][1024] bf16 (WqkvT then WoT).
__global__ __launch_bounds__(256) void transpose_w4(
    const float* __restrict__ Wq, const float* __restrict__ Wk,
    const float* __restrict__ Wv, const float* __restrict__ Wo,
    __hip_bfloat16* __restrict__ out)
{
  __shared__ float tile[32][33];
  const int z = blockIdx.z;
  const float* W = z == 0 ? Wq : z == 1 ? Wk : z == 2 ? Wv : Wo;
  const int n0 = blockIdx.x * 32, k0 = blockIdx.y * 32;
  const int tx = threadIdx.x, ty = threadIdx.y;  // 32 x 8
#pragma unroll
  for (int i = 0; i < 32; i += 8)
    tile[ty + i][tx] = W[(size_t)(k0 + ty + i) * 1024 + n0 + tx];
  __syncthreads();
  __hip_bfloat16* o = out + (size_t)z * 1024 * 1024;
#pragma unroll
  for (int i = 0; i < 32; i += 8)
    o[(size_t)(n0 + ty + i) * 1024 + k0 + tx] = __float2bfloat16(tile[tx][ty + i]);
}

// ---------------- generic weight transpose ----------------------------------
__global__ __launch_bounds__(256) void transpose_w(
    const float* __restrict__ W, __hip_bfloat16* __restrict__ WT,
    int K, int N, int ldo)
{
  __shared__ float tile[32][33];
  const int n0 = blockIdx.x * 32, k0 = blockIdx.y * 32;
  const int tx = threadIdx.x, ty = threadIdx.y;  // 32 x 8
#pragma unroll
  for (int i = 0; i < 32; i += 8)
    tile[ty + i][tx] = W[(size_t)(k0 + ty + i) * N + n0 + tx];
  __syncthreads();
#pragma unroll
  for (int i = 0; i < 32; i += 8)
    WT[(size_t)(n0 + ty + i) * ldo + k0 + tx] = __float2bfloat16(tile[tx][ty + i]);
}

// ---------------- V transpose: QKV V-part -> VTg[b][h][d][t] ---------------
__global__ __launch_bounds__(256) void transpose_v(
    const __hip_bfloat16* __restrict__ QKV, __hip_bfloat16* __restrict__ VTg)
{
  __shared__ float tile[32][33];
  const int t0 = blockIdx.x * 32;
  const int bh = blockIdx.y >> 1;
  const int dt = (blockIdx.y & 1) * 32;
  const int b = bh >> 4, h = bh & 15;
  const int tx = threadIdx.x, ty = threadIdx.y;  // 32 x 8
#pragma unroll
  for (int i = 0; i < 32; i += 8)
    tile[ty + i][tx] = __bfloat162float(
        QKV[(size_t)(b * T_SEQ + t0 + ty + i) * 3072 + 2048 + h * 64 + dt + tx]);
  __syncthreads();
#pragma unroll
  for (int i = 0; i < 32; i += 8)
    VTg[((size_t)bh * 64 + dt + ty + i) * T_SEQ + t0 + tx] =
        __float2bfloat16(tile[tx][ty + i]);
}

// ---------------- RMSNorm (fp32 in -> bf16 out) ----------------------------
__global__ __launch_bounds__(256) void rmsnorm_kernel(
    const float* __restrict__ x, const float* __restrict__ g,
    __hip_bfloat16* __restrict__ out)
{
  const int row = blockIdx.x;
  const int t = threadIdx.x;
  const float4 v = ((const float4*)(x + (size_t)row * 1024))[t];
  float ss = v.x * v.x + v.y * v.y + v.z * v.z + v.w * v.w;
#pragma unroll
  for (int off = 32; off; off >>= 1) ss += __shfl_xor(ss, off, 64);
  __shared__ float red[4];
  if ((t & 63) == 0) red[t >> 6] = ss;
  __syncthreads();
  ss = red[0] + red[1] + red[2] + red[3];
  const float rs = rsqrtf(ss * (1.0f / 1024.0f) + 1e-6f);
  const float4 gv = ((const float4*)g)[t];
  __hip_bfloat16* o = out + (size_t)row * 1024 + t * 4;
  o[0] = __float2bfloat16(v.x * rs * gv.x);
  o[1] = __float2bfloat16(v.y * rs * gv.y);
  o[2] = __float2bfloat16(v.z * rs * gv.z);
  o[3] = __float2bfloat16(v.w * rs * gv.w);
}

// ---------------- GEMM: C = A @ BT^T (+epilogue), pipelined K-loop ----------
// A [M][K] bf16, BT [N][K] bf16. Tile (32*MT)x128, BK=64, 4 waves 2x2.
// Pipeline: regs hold tile k+1 while LDS holds tile k; barriers drain LDS
// counters only — the global loads stay in flight through the MFMA block.
// MODE 0: outb = bf16(C)              MODE 1: outf = resid + C
// MODE 2: outb = bf16(gelu(C+bias))   MODE 3: outf = resid + C + bias
template <int MODE, int MT>
__global__ __launch_bounds__(256, MT == 4 ? 3 : 4) void gemm_bt(
    const __hip_bfloat16* __restrict__ A,
    const __hip_bfloat16* __restrict__ BT,
    const float* __restrict__ bias,
    const float* __restrict__ resid,
    __hip_bfloat16* __restrict__ outb,
    float* __restrict__ outf,
    int M, int N, int K)
{
  __shared__ __align__(16) __hip_bfloat16 As[32 * MT * 64];
  __shared__ __align__(16) __hip_bfloat16 Bs[128 * 64];
  const int tid = threadIdx.x;
  const int wave = tid >> 6, lane = tid & 63;
  const int quad = lane >> 4, l16 = lane & 15;
  const int m0 = blockIdx.y * (32 * MT), n0 = blockIdx.x * 128;
  const int wr = (wave >> 1) * (16 * MT), wc = (wave & 1) * 64;
  const int lrow = lane >> 3;                    // row within 8-row chunk
  const int gcol = (lane & 7) * 8;               // natural global col
  const int swoff = ((lane & 7) ^ lrow) * 8;     // swizzled LDS col

  // per-thread staging addresses (chunk c covers rows c*8..c*8+7)
  const __hip_bfloat16* agp[MT];
  const __hip_bfloat16* bgp[4];
  __hip_bfloat16* alp[MT];
  __hip_bfloat16* blp[4];
#pragma unroll
  for (int i = 0; i < MT; i++) {
    const int c = wave * MT + i;
    agp[i] = A + (size_t)(m0 + c * 8 + lrow) * K + gcol;
    alp[i] = As + c * 512 + lrow * 64 + swoff;
  }
#pragma unroll
  for (int i = 0; i < 4; i++) {
    const int c = wave * 4 + i;
    bgp[i] = BT + (size_t)(n0 + c * 8 + lrow) * K + gcol;
    blp[i] = Bs + c * 512 + lrow * 64 + swoff;
  }

  uint4 ra[MT], rb[4];
  auto gload = [&](int k0) {
#pragma unroll
    for (int i = 0; i < MT; i++) ra[i] = *(const uint4*)(agp[i] + k0);
#pragma unroll
    for (int i = 0; i < 4; i++) rb[i] = *(const uint4*)(bgp[i] + k0);
  };

  v4f acc[MT][4];
#pragma unroll
  for (int i = 0; i < MT; i++)
#pragma unroll
    for (int j = 0; j < 4; j++)
#pragma unroll
      for (int c = 0; c < 4; c++) acc[i][j][c] = 0.0f;

  gload(0);
  for (int k0 = 0; k0 < K; k0 += 64) {
    __syncthreads();  // all waves done reading LDS tile k-1
#pragma unroll
    for (int i = 0; i < MT; i++) *(uint4*)alp[i] = ra[i];
#pragma unroll
    for (int i = 0; i < 4; i++) *(uint4*)blp[i] = rb[i];
    __syncthreads();  // tile k visible
    if (k0 + 64 < K) gload(k0 + 64);  // in flight through the MFMA block
#pragma unroll
    for (int ks = 0; ks < 64; ks += 32) {
      v8bf af[MT], bf[4];
#pragma unroll
      for (int mt = 0; mt < MT; mt++)
        af[mt] = FRAG(As, wr + mt * 16 + l16, ks + quad * 8);
#pragma unroll
      for (int nt = 0; nt < 4; nt++)
        bf[nt] = FRAG(Bs, wc + nt * 16 + l16, ks + quad * 8);
#pragma unroll
      for (int mt = 0; mt < MT; mt++)
#pragma unroll
        for (int nt = 0; nt < 4; nt++)
          acc[mt][nt] = __builtin_amdgcn_mfma_f32_16x16x32_bf16(
              af[mt], bf[nt], acc[mt][nt], 0, 0, 0);
    }
  }

  // epilogue: C/D layout col=lane&15, row=quad*4+reg
#pragma unroll
  for (int mt = 0; mt < MT; mt++) {
#pragma unroll
    for (int r = 0; r < 4; r++) {
      const int gm = m0 + wr + mt * 16 + quad * 4 + r;
#pragma unroll
      for (int nt = 0; nt < 4; nt++) {
        const int gn = n0 + wc + nt * 16 + l16;
        float v = acc[mt][nt][r];
        if (MODE == 0) {
          outb[(size_t)gm * N + gn] = __float2bfloat16(v);
        } else if (MODE == 1) {
          outf[(size_t)gm * N + gn] = resid[(size_t)gm * N + gn] + v;
        } else if (MODE == 2) {
          v += bias[gn];
          v = 0.5f * v * (1.0f + erff(v * 0.70710678118654752f));
          outb[(size_t)gm * N + gn] = __float2bfloat16(v);
        } else {
          v += bias[gn];
          outf[(size_t)gm * N + gn] = resid[(size_t)gm * N + gn] + v;
        }
      }
    }
  }
}

// ---------------- flash attention (causal, no-max exp2 softmax) ------------
// One block = q-tile pair (qa=p, qb=31-p) for one (b,h): uniform 33 k-tiles.
__global__ __launch_bounds__(256, 2) void attn_kernel(
    const __hip_bfloat16* __restrict__ QKV,
    const __hip_bfloat16* __restrict__ VTg,
    __hip_bfloat16* __restrict__ Y)
{
  __shared__ __align__(16) __hip_bfloat16 Ks[2 * 64 * 64];  // [buf][krow][d] swz
  __shared__ __align__(16) __hip_bfloat16 Vs[2 * 64 * 64];  // [buf][d][krow] swz
  __shared__ __align__(16) __hip_bfloat16 PsA[64 * 64];     // [qrow][krow] swz
  __shared__ __align__(16) __hip_bfloat16 PsB[64 * 64];

  const int tid = threadIdx.x;
  const int wave = tid >> 6, lane = tid & 63;
  const int quad = lane >> 4, l16 = lane & 15;
  const int blk = blockIdx.x;
  const int p = blk & 15, h = (blk >> 4) & 15, b = blk >> 8;
  const int qa = p, qb = 31 - p, kmax = qb;
  const size_t rowbase = (size_t)b * T_SEQ;
  const size_t vbase = (size_t)(b * 16 + h) * 64;
  const int lrow = lane >> 3, scol = ((lane & 7) ^ (lane >> 3)) * 8;

  const float QSC = 0.125f * 1.44269504f;
  v8bf aqA[2], aqB[2];
#pragma unroll
  for (int ks = 0; ks < 2; ks++) {
    v8bf q = *(const v8bf*)(QKV + (rowbase + qa * 64 + wave * 16 + l16) * 3072 +
                            h * 64 + ks * 32 + quad * 8);
#pragma unroll
    for (int j = 0; j < 8; j++) aqA[ks][j] = (__bf16)((float)q[j] * QSC);
    q = *(const v8bf*)(QKV + (rowbase + qb * 64 + wave * 16 + l16) * 3072 +
                       h * 64 + ks * 32 + quad * 8);
#pragma unroll
    for (int j = 0; j < 8; j++) aqB[ks][j] = (__bf16)((float)q[j] * QSC);
  }

  v4f oA[4], oB[4];
  float lpA[4], lpB[4];
#pragma unroll
  for (int i = 0; i < 4; i++) {
    lpA[i] = 0.0f; lpB[i] = 0.0f;
#pragma unroll
    for (int c = 0; c < 4; c++) { oA[i][c] = 0.0f; oB[i][c] = 0.0f; }
  }

  auto stage = [&](int kt, int buf) {
#pragma unroll
    for (int i = 0; i < 2; i++) {
      const int r8 = i * 32 + wave * 8;
      const int rr = r8 + lrow;
      async_ld16(QKV + (rowbase + kt * 64 + rr) * 3072 + 1024 + h * 64 + scol,
                 Ks + buf * 4096 + r8 * 64);
      async_ld16(VTg + (vbase + rr) * T_SEQ + kt * 64 + scol,
                 Vs + buf * 4096 + r8 * 64);
    }
  };
  stage(0, 0);

  auto softmax_store = [&](v4f s[4], float lp[4], __hip_bfloat16* Ps, bool diag) {
    if (diag) {
#pragma unroll
      for (int nt = 0; nt < 4; nt++) {
        const int colr = nt * 16 + l16;
#pragma unroll
        for (int r = 0; r < 4; r++)
          if (colr > wave * 16 + quad * 4 + r) s[nt][r] = -30000.0f;
      }
    }
#pragma unroll
    for (int r = 0; r < 4; r++) {
      const int row = wave * 16 + quad * 4 + r;
      const int rsw = (quad * 4 + r) & 7;
#pragma unroll
      for (int nt = 0; nt < 4; nt++) {
        const float e = EXP2F(s[nt][r]);
        lp[r] += e;
        const int chunk = (nt * 2 + (l16 >> 3)) ^ rsw;
        Ps[row * 64 + (chunk << 3) + (l16 & 7)] = __float2bfloat16(e);
      }
    }
  };

  for (int kt = 0; kt <= kmax; kt++) {
    __syncthreads();
    if (kt < kmax) stage(kt + 1, (kt + 1) & 1);
    const __hip_bfloat16* Kb = Ks + (kt & 1) * 4096;
    const __hip_bfloat16* Vb = Vs + (kt & 1) * 4096;
    const bool doA = (kt <= qa);

    {
      v8bf kf[2][4];
#pragma unroll
      for (int ks = 0; ks < 2; ks++)
#pragma unroll
        for (int nt = 0; nt < 4; nt++)
          kf[ks][nt] = FRAG(Kb, nt * 16 + l16, ks * 32 + quad * 8);

      v4f sB[4];
#pragma unroll
      for (int nt = 0; nt < 4; nt++)
#pragma unroll
        for (int c = 0; c < 4; c++) sB[nt][c] = 0.0f;
#pragma unroll
      for (int ks = 0; ks < 2; ks++)
#pragma unroll
        for (int nt = 0; nt < 4; nt++)
          sB[nt] = __builtin_amdgcn_mfma_f32_16x16x32_bf16(aqB[ks], kf[ks][nt],
                                                           sB[nt], 0, 0, 0);
      softmax_store(sB, lpB, PsB, kt == qb);

      if (doA) {
        v4f sA[4];
#pragma unroll
        for (int nt = 0; nt < 4; nt++)
#pragma unroll
          for (int c = 0; c < 4; c++) sA[nt][c] = 0.0f;
#pragma unroll
        for (int ks = 0; ks < 2; ks++)
#pragma unroll
          for (int nt = 0; nt < 4; nt++)
            sA[nt] = __builtin_amdgcn_mfma_f32_16x16x32_bf16(aqA[ks], kf[ks][nt],
                                                             sA[nt], 0, 0, 0);
        softmax_store(sA, lpA, PsA, kt == qa);
      }
    }

    {
      v8bf vf[2][4];
#pragma unroll
      for (int ks = 0; ks < 2; ks++)
#pragma unroll
        for (int nt = 0; nt < 4; nt++)
          vf[ks][nt] = FRAG(Vb, nt * 16 + l16, ks * 32 + quad * 8);
#pragma unroll
      for (int ks = 0; ks < 2; ks++) {
        const v8bf apB = FRAG(PsB, wave * 16 + l16, ks * 32 + quad * 8);
#pragma unroll
        for (int nt = 0; nt < 4; nt++)
          oB[nt] = __builtin_amdgcn_mfma_f32_16x16x32_bf16(apB, vf[ks][nt],
                                                           oB[nt], 0, 0, 0);
      }
      if (doA) {
#pragma unroll
        for (int ks = 0; ks < 2; ks++) {
          const v8bf apA = FRAG(PsA, wave * 16 + l16, ks * 32 + quad * 8);
#pragma unroll
          for (int nt = 0; nt < 4; nt++)
            oA[nt] = __builtin_amdgcn_mfma_f32_16x16x32_bf16(apA, vf[ks][nt],
                                                             oA[nt], 0, 0, 0);
        }
      }
    }
  }

#pragma unroll
  for (int r = 0; r < 4; r++) {
    float la = lpA[r], lb = lpB[r];
#pragma unroll
    for (int off = 1; off < 16; off <<= 1) {
      la += __shfl_xor(la, off, 16);
      lb += __shfl_xor(lb, off, 16);
    }
    const float ila = 1.0f / la, ilb = 1.0f / lb;
#pragma unroll
    for (int nt = 0; nt < 4; nt++) {
      Y[(rowbase + qa * 64 + wave * 16 + quad * 4 + r) * 1024 + h * 64 + nt * 16 + l16] =
          __float2bfloat16(oA[nt][r] * ila);
      Y[(rowbase + qb * 64 + wave * 16 + quad * 4 + r) * 1024 + h * 64 + nt * 16 + l16] =
          __float2bfloat16(oB[nt][r] * ilb);
    }
  }
}

// ---------------------------------------------------------------------------
extern "C" void kernel_launch(void* const* d_in, const int* in_sizes, int n_in,
                              void* d_out, int out_size, void* d_ws, size_t ws_size,
                              hipStream_t stream)
{
  const float* x  = (const float*)d_in[0];
  const float* Wq = (const float*)d_in[1];
  const float* Wk = (const float*)d_in[2];
  const float* Wv = (const float*)d_in[3];
  const float* Wo = (const float*)d_in[4];
  const float* W1 = (const float*)d_in[5];
  const float* b1 = (const float*)d_in[6];
  const float* W2 = (const float*)d_in[7];
  const float* b2 = (const float*)d_in[8];
  const float* g1 = (const float*)d_in[9];
  const float* g2 = (const float*)d_in[10];

  uint8_t* ws = (uint8_t*)d_ws;
  __hip_bfloat16* WqkvT = (__hip_bfloat16*)(ws + 0);         // [3072][1024] 6 MB
  __hip_bfloat16* WoT   = (__hip_bfloat16*)(ws + 6291456);   // [1024][1024] 2 MB
  __hip_bfloat16* W1T   = (__hip_bfloat16*)(ws + 8388608);   // [4096][1024] 8 MB
  __hip_bfloat16* W2T   = (__hip_bfloat16*)(ws + 16777216);  // [1024][4096] 8 MB
  float*          x1    = (float*)(ws + 25165824);           // [4096][1024] 16 MB
  __hip_bfloat16* VTg   = (__hip_bfloat16*)(ws + 25165824);  // overlay on x1
  __hip_bfloat16* xn    = (__hip_bfloat16*)(ws + 41943040);  // [4096][1024] 8 MB
  __hip_bfloat16* QKV   = (__hip_bfloat16*)(ws + 50331648);  // [4096][3072] 24 MB
  __hip_bfloat16* Ybuf  = (__hip_bfloat16*)(ws + 75497472);  // [4096][1024] 8 MB
  __hip_bfloat16* Hbuf  = (__hip_bfloat16*)(ws + 50331648);  // overlay on QKV+Y

  const dim3 tb(32, 8);
  transpose_w4<<<dim3(32, 32, 4), tb, 0, stream>>>(Wq, Wk, Wv, Wo, WqkvT);
  transpose_w<<<dim3(128, 32), tb, 0, stream>>>(W1, W1T, 1024, 4096, 1024);
  transpose_w<<<dim3(32, 128), tb, 0, stream>>>(W2, W2T, 4096, 1024, 4096);

  rmsnorm_kernel<<<4096, 256, 0, stream>>>(x, g1, xn);
  gemm_bt<0, 4><<<dim3(24, 32), 256, 0, stream>>>(xn, WqkvT, nullptr, nullptr, QKV,
                                                  nullptr, 4096, 3072, 1024);
  transpose_v<<<dim3(64, 64), tb, 0, stream>>>(QKV, VTg);
  attn_kernel<<<512, 256, 0, stream>>>(QKV, VTg, Ybuf);
  gemm_bt<1, 2><<<dim3(8, 64), 256, 0, stream>>>(Ybuf, WoT, nullptr, x, nullptr, x1,
                                                 4096, 1024, 1024);
  rmsnorm_kernel<<<4096, 256, 0, stream>>>(x1, g2, xn);
  gemm_bt<2, 4><<<dim3(32, 32), 256, 0, stream>>>(xn, W1T, b1, nullptr, Hbuf, nullptr,
                                                  4096, 4096, 1024);
  gemm_bt<3, 2><<<dim3(8, 64), 256, 0, stream>>>(Hbuf, W2T, b2, x1, nullptr,
                                                 (float*)d_out, 4096, 1024, 4096);
}

// Round 6
// 346.361 us; speedup vs baseline: 2.2382x; 2.2382x over previous
//
#include <hip/hip_runtime.h>
#include <hip/hip_bf16.h>
#include <math.h>
#include <stdint.h>

// ---------------------------------------------------------------------------
// Transformer block: x + attn(rms(x,g1)) -> x1 ; x1 + ffn(rms(x1,g2))
// B=2 T=2048 D=1024 H=16 Dh=64 FF=4096. All GEMMs bf16 MFMA 16x16x32.
// GEMM K-loop = round-4 structure (global_load_lds width-16, 2-barrier) —
// manual VGPR pipelining spilled to scratch (R5: WRITE_SIZE 16->283MB), so
// we keep the compiler-friendly loop and add parallelism via split-K instead.
// LDS tiles use XOR-swizzled 16B chunks (chunk j of row r lives at j^(r&7)).
// ---------------------------------------------------------------------------

typedef __bf16 v8bf  __attribute__((ext_vector_type(8)));
typedef float  v4f   __attribute__((ext_vector_type(4)));

#define T_SEQ 2048
#define EXP2F(x) __builtin_amdgcn_exp2f(x)  // v_exp_f32 (2^x)

// swizzled fragment read: row R, k-elem offset ko (multiple of 8)
#define FRAG(base, R, ko) \
  (*(const v8bf*)((base) + (R) * 64 + (((((ko) >> 3) ^ ((R) & 7))) << 3)))

__device__ __forceinline__ void async_ld16(const void* g, void* l) {
  // global -> LDS direct, 16B/lane. LDS dest is wave-uniform base + lane*16.
  __builtin_amdgcn_global_load_lds(
      (const __attribute__((address_space(1))) uint32_t*)g,
      (__attribute__((address_space(3))) uint32_t*)l, 16, 0, 0);
}

// ---------------- 4x weight transpose (Wq,Wk,Wv,Wo) fused ------------------
// out is contiguous [4][1024][1024] bf16 (WqkvT then WoT).
__global__ __launch_bounds__(256) void transpose_w4(
    const float* __restrict__ Wq, const float* __restrict__ Wk,
    const float* __restrict__ Wv, const float* __restrict__ Wo,
    __hip_bfloat16* __restrict__ out)
{
  __shared__ float tile[32][33];
  const int z = blockIdx.z;
  const float* W = z == 0 ? Wq : z == 1 ? Wk : z == 2 ? Wv : Wo;
  const int n0 = blockIdx.x * 32, k0 = blockIdx.y * 32;
  const int tx = threadIdx.x, ty = threadIdx.y;  // 32 x 8
#pragma unroll
  for (int i = 0; i < 32; i += 8)
    tile[ty + i][tx] = W[(size_t)(k0 + ty + i) * 1024 + n0 + tx];
  __syncthreads();
  __hip_bfloat16* o = out + (size_t)z * 1024 * 1024;
#pragma unroll
  for (int i = 0; i < 32; i += 8)
    o[(size_t)(n0 + ty + i) * 1024 + k0 + tx] = __float2bfloat16(tile[tx][ty + i]);
}

// ---------------- generic weight transpose ----------------------------------
__global__ __launch_bounds__(256) void transpose_w(
    const float* __restrict__ W, __hip_bfloat16* __restrict__ WT,
    int K, int N, int ldo)
{
  __shared__ float tile[32][33];
  const int n0 = blockIdx.x * 32, k0 = blockIdx.y * 32;
  const int tx = threadIdx.x, ty = threadIdx.y;  // 32 x 8
#pragma unroll
  for (int i = 0; i < 32; i += 8)
    tile[ty + i][tx] = W[(size_t)(k0 + ty + i) * N + n0 + tx];
  __syncthreads();
#pragma unroll
  for (int i = 0; i < 32; i += 8)
    WT[(size_t)(n0 + ty + i) * ldo + k0 + tx] = __float2bfloat16(tile[tx][ty + i]);
}

// ---------------- V transpose: QKV V-part -> VTg[b][h][d][t] ---------------
__global__ __launch_bounds__(256) void transpose_v(
    const __hip_bfloat16* __restrict__ QKV, __hip_bfloat16* __restrict__ VTg)
{
  __shared__ float tile[32][33];
  const int t0 = blockIdx.x * 32;
  const int bh = blockIdx.y >> 1;
  const int dt = (blockIdx.y & 1) * 32;
  const int b = bh >> 4, h = bh & 15;
  const int tx = threadIdx.x, ty = threadIdx.y;  // 32 x 8
#pragma unroll
  for (int i = 0; i < 32; i += 8)
    tile[ty + i][tx] = __bfloat162float(
        QKV[(size_t)(b * T_SEQ + t0 + ty + i) * 3072 + 2048 + h * 64 + dt + tx]);
  __syncthreads();
#pragma unroll
  for (int i = 0; i < 32; i += 8)
    VTg[((size_t)bh * 64 + dt + ty + i) * T_SEQ + t0 + tx] =
        __float2bfloat16(tile[tx][ty + i]);
}

// ---------------- RMSNorm (fp32 in -> bf16 out, optional d_out init) -------
// if dinit != nullptr: dinit[row] = x[row] + bias  (pre-initializes the
// split-K atomic target with residual+bias; C partials are atomicAdd'ed).
__global__ __launch_bounds__(256) void rmsnorm_kernel(
    const float* __restrict__ x, const float* __restrict__ g,
    __hip_bfloat16* __restrict__ out,
    const float* __restrict__ bias, float* __restrict__ dinit)
{
  const int row = blockIdx.x;
  const int t = threadIdx.x;
  const float4 v = ((const float4*)(x + (size_t)row * 1024))[t];
  float ss = v.x * v.x + v.y * v.y + v.z * v.z + v.w * v.w;
#pragma unroll
  for (int off = 32; off; off >>= 1) ss += __shfl_xor(ss, off, 64);
  __shared__ float red[4];
  if ((t & 63) == 0) red[t >> 6] = ss;
  __syncthreads();
  ss = red[0] + red[1] + red[2] + red[3];
  const float rs = rsqrtf(ss * (1.0f / 1024.0f) + 1e-6f);
  const float4 gv = ((const float4*)g)[t];
  __hip_bfloat16* o = out + (size_t)row * 1024 + t * 4;
  o[0] = __float2bfloat16(v.x * rs * gv.x);
  o[1] = __float2bfloat16(v.y * rs * gv.y);
  o[2] = __float2bfloat16(v.z * rs * gv.z);
  o[3] = __float2bfloat16(v.w * rs * gv.w);
  if (dinit) {
    const float4 bv = ((const float4*)bias)[t];
    float4 d;
    d.x = v.x + bv.x; d.y = v.y + bv.y; d.z = v.z + bv.z; d.w = v.w + bv.w;
    ((float4*)(dinit + (size_t)row * 1024))[t] = d;
  }
}

// ---------------- GEMM: C = A @ BT^T (+epilogue) ---------------------------
// A [M][K] bf16, BT [N][K] bf16. Tile (32*MT)x128, BK=64, 4 waves 2x2.
// Ksub = K-extent per block (split-K via blockIdx.z; kb = z*Ksub).
// MODE 0: outb = bf16(C)              MODE 1: outf = resid + C
// MODE 2: outb = bf16(gelu(C+bias))   MODE 4: atomicAdd(outf, C)
template <int MODE, int MT>
__global__ __launch_bounds__(256, 2) void gemm_bt(
    const __hip_bfloat16* __restrict__ A,
    const __hip_bfloat16* __restrict__ BT,
    const float* __restrict__ bias,
    const float* __restrict__ resid,
    __hip_bfloat16* __restrict__ outb,
    float* __restrict__ outf,
    int M, int N, int K, int Ksub)
{
  __shared__ __align__(16) __hip_bfloat16 As[32 * MT * 64];
  __shared__ __align__(16) __hip_bfloat16 Bs[128 * 64];
  const int tid = threadIdx.x;
  const int wave = tid >> 6, lane = tid & 63;
  const int quad = lane >> 4, l16 = lane & 15;
  const int m0 = blockIdx.y * (32 * MT), n0 = blockIdx.x * 128;
  const size_t kb = (size_t)blockIdx.z * Ksub;
  const int wr = (wave >> 1) * (16 * MT), wc = (wave & 1) * 64;
  const int lrow = lane >> 3;                 // row within 8-row chunk
  const int scol = ((lane & 7) ^ lrow) * 8;   // swizzled global col fetch

  v4f acc[MT][4];
#pragma unroll
  for (int i = 0; i < MT; i++)
#pragma unroll
    for (int j = 0; j < 4; j++)
#pragma unroll
      for (int c = 0; c < 4; c++) acc[i][j][c] = 0.0f;

  for (int k0 = 0; k0 < Ksub; k0 += 64) {
#pragma unroll
    for (int i = 0; i < MT + 4; i++) {
      const int c = wave * (MT + 4) + i;
      if (c < 4 * MT) {
        async_ld16(A + (size_t)(m0 + c * 8 + lrow) * K + kb + k0 + scol, As + c * 512);
      } else {
        const int cb = c - 4 * MT;
        async_ld16(BT + (size_t)(n0 + cb * 8 + lrow) * K + kb + k0 + scol,
                   Bs + cb * 512);
      }
    }
    __syncthreads();
#pragma unroll
    for (int ks = 0; ks < 64; ks += 32) {
      v8bf af[MT], bf[4];
#pragma unroll
      for (int mt = 0; mt < MT; mt++)
        af[mt] = FRAG(As, wr + mt * 16 + l16, ks + quad * 8);
#pragma unroll
      for (int nt = 0; nt < 4; nt++)
        bf[nt] = FRAG(Bs, wc + nt * 16 + l16, ks + quad * 8);
#pragma unroll
      for (int mt = 0; mt < MT; mt++)
#pragma unroll
        for (int nt = 0; nt < 4; nt++)
          acc[mt][nt] = __builtin_amdgcn_mfma_f32_16x16x32_bf16(
              af[mt], bf[nt], acc[mt][nt], 0, 0, 0);
    }
    __syncthreads();
  }

  // epilogue: C/D layout col=lane&15, row=quad*4+reg
#pragma unroll
  for (int mt = 0; mt < MT; mt++) {
#pragma unroll
    for (int r = 0; r < 4; r++) {
      const int gm = m0 + wr + mt * 16 + quad * 4 + r;
#pragma unroll
      for (int nt = 0; nt < 4; nt++) {
        const int gn = n0 + wc + nt * 16 + l16;
        float v = acc[mt][nt][r];
        if (MODE == 0) {
          outb[(size_t)gm * N + gn] = __float2bfloat16(v);
        } else if (MODE == 1) {
          outf[(size_t)gm * N + gn] = resid[(size_t)gm * N + gn] + v;
        } else if (MODE == 2) {
          v += bias[gn];
          v = 0.5f * v * (1.0f + erff(v * 0.70710678118654752f));
          outb[(size_t)gm * N + gn] = __float2bfloat16(v);
        } else {
          atomicAdd(&outf[(size_t)gm * N + gn], v);
        }
      }
    }
  }
}

// ---------------- flash attention (causal, no-max exp2 softmax) ------------
// One block = q-tile pair (qa=p, qb=31-p) for one (b,h): uniform 33 k-tiles.
__global__ __launch_bounds__(256, 2) void attn_kernel(
    const __hip_bfloat16* __restrict__ QKV,
    const __hip_bfloat16* __restrict__ VTg,
    __hip_bfloat16* __restrict__ Y)
{
  __shared__ __align__(16) __hip_bfloat16 Ks[2 * 64 * 64];  // [buf][krow][d] swz
  __shared__ __align__(16) __hip_bfloat16 Vs[2 * 64 * 64];  // [buf][d][krow] swz
  __shared__ __align__(16) __hip_bfloat16 PsA[64 * 64];     // [qrow][krow] swz
  __shared__ __align__(16) __hip_bfloat16 PsB[64 * 64];

  const int tid = threadIdx.x;
  const int wave = tid >> 6, lane = tid & 63;
  const int quad = lane >> 4, l16 = lane & 15;
  const int blk = blockIdx.x;
  const int p = blk & 15, h = (blk >> 4) & 15, b = blk >> 8;
  const int qa = p, qb = 31 - p, kmax = qb;
  const size_t rowbase = (size_t)b * T_SEQ;
  const size_t vbase = (size_t)(b * 16 + h) * 64;
  const int lrow = lane >> 3, scol = ((lane & 7) ^ (lane >> 3)) * 8;

  const float QSC = 0.125f * 1.44269504f;
  v8bf aqA[2], aqB[2];
#pragma unroll
  for (int ks = 0; ks < 2; ks++) {
    v8bf q = *(const v8bf*)(QKV + (rowbase + qa * 64 + wave * 16 + l16) * 3072 +
                            h * 64 + ks * 32 + quad * 8);
#pragma unroll
    for (int j = 0; j < 8; j++) aqA[ks][j] = (__bf16)((float)q[j] * QSC);
    q = *(const v8bf*)(QKV + (rowbase + qb * 64 + wave * 16 + l16) * 3072 +
                       h * 64 + ks * 32 + quad * 8);
#pragma unroll
    for (int j = 0; j < 8; j++) aqB[ks][j] = (__bf16)((float)q[j] * QSC);
  }

  v4f oA[4], oB[4];
  float lpA[4], lpB[4];
#pragma unroll
  for (int i = 0; i < 4; i++) {
    lpA[i] = 0.0f; lpB[i] = 0.0f;
#pragma unroll
    for (int c = 0; c < 4; c++) { oA[i][c] = 0.0f; oB[i][c] = 0.0f; }
  }

  auto stage = [&](int kt, int buf) {
#pragma unroll
    for (int i = 0; i < 2; i++) {
      const int r8 = i * 32 + wave * 8;
      const int rr = r8 + lrow;
      async_ld16(QKV + (rowbase + kt * 64 + rr) * 3072 + 1024 + h * 64 + scol,
                 Ks + buf * 4096 + r8 * 64);
      async_ld16(VTg + (vbase + rr) * T_SEQ + kt * 64 + scol,
                 Vs + buf * 4096 + r8 * 64);
    }
  };
  stage(0, 0);

  auto softmax_store = [&](v4f s[4], float lp[4], __hip_bfloat16* Ps, bool diag) {
    if (diag) {
#pragma unroll
      for (int nt = 0; nt < 4; nt++) {
        const int colr = nt * 16 + l16;
#pragma unroll
        for (int r = 0; r < 4; r++)
          if (colr > wave * 16 + quad * 4 + r) s[nt][r] = -30000.0f;
      }
    }
#pragma unroll
    for (int r = 0; r < 4; r++) {
      const int row = wave * 16 + quad * 4 + r;
      const int rsw = (quad * 4 + r) & 7;
#pragma unroll
      for (int nt = 0; nt < 4; nt++) {
        const float e = EXP2F(s[nt][r]);
        lp[r] += e;
        const int chunk = (nt * 2 + (l16 >> 3)) ^ rsw;
        Ps[row * 64 + (chunk << 3) + (l16 & 7)] = __float2bfloat16(e);
      }
    }
  };

  for (int kt = 0; kt <= kmax; kt++) {
    __syncthreads();
    if (kt < kmax) stage(kt + 1, (kt + 1) & 1);
    const __hip_bfloat16* Kb = Ks + (kt & 1) * 4096;
    const __hip_bfloat16* Vb = Vs + (kt & 1) * 4096;
    const bool doA = (kt <= qa);

    {
      v8bf kf[2][4];
#pragma unroll
      for (int ks = 0; ks < 2; ks++)
#pragma unroll
        for (int nt = 0; nt < 4; nt++)
          kf[ks][nt] = FRAG(Kb, nt * 16 + l16, ks * 32 + quad * 8);

      v4f sB[4];
#pragma unroll
      for (int nt = 0; nt < 4; nt++)
#pragma unroll
        for (int c = 0; c < 4; c++) sB[nt][c] = 0.0f;
#pragma unroll
      for (int ks = 0; ks < 2; ks++)
#pragma unroll
        for (int nt = 0; nt < 4; nt++)
          sB[nt] = __builtin_amdgcn_mfma_f32_16x16x32_bf16(aqB[ks], kf[ks][nt],
                                                           sB[nt], 0, 0, 0);
      softmax_store(sB, lpB, PsB, kt == qb);

      if (doA) {
        v4f sA[4];
#pragma unroll
        for (int nt = 0; nt < 4; nt++)
#pragma unroll
          for (int c = 0; c < 4; c++) sA[nt][c] = 0.0f;
#pragma unroll
        for (int ks = 0; ks < 2; ks++)
#pragma unroll
          for (int nt = 0; nt < 4; nt++)
            sA[nt] = __builtin_amdgcn_mfma_f32_16x16x32_bf16(aqA[ks], kf[ks][nt],
                                                             sA[nt], 0, 0, 0);
        softmax_store(sA, lpA, PsA, kt == qa);
      }
    }

    {
      v8bf vf[2][4];
#pragma unroll
      for (int ks = 0; ks < 2; ks++)
#pragma unroll
        for (int nt = 0; nt < 4; nt++)
          vf[ks][nt] = FRAG(Vb, nt * 16 + l16, ks * 32 + quad * 8);
#pragma unroll
      for (int ks = 0; ks < 2; ks++) {
        const v8bf apB = FRAG(PsB, wave * 16 + l16, ks * 32 + quad * 8);
#pragma unroll
        for (int nt = 0; nt < 4; nt++)
          oB[nt] = __builtin_amdgcn_mfma_f32_16x16x32_bf16(apB, vf[ks][nt],
                                                           oB[nt], 0, 0, 0);
      }
      if (doA) {
#pragma unroll
        for (int ks = 0; ks < 2; ks++) {
          const v8bf apA = FRAG(PsA, wave * 16 + l16, ks * 32 + quad * 8);
#pragma unroll
          for (int nt = 0; nt < 4; nt++)
            oA[nt] = __builtin_amdgcn_mfma_f32_16x16x32_bf16(apA, vf[ks][nt],
                                                             oA[nt], 0, 0, 0);
        }
      }
    }
  }

#pragma unroll
  for (int r = 0; r < 4; r++) {
    float la = lpA[r], lb = lpB[r];
#pragma unroll
    for (int off = 1; off < 16; off <<= 1) {
      la += __shfl_xor(la, off, 16);
      lb += __shfl_xor(lb, off, 16);
    }
    const float ila = 1.0f / la, ilb = 1.0f / lb;
#pragma unroll
    for (int nt = 0; nt < 4; nt++) {
      Y[(rowbase + qa * 64 + wave * 16 + quad * 4 + r) * 1024 + h * 64 + nt * 16 + l16] =
          __float2bfloat16(oA[nt][r] * ila);
      Y[(rowbase + qb * 64 + wave * 16 + quad * 4 + r) * 1024 + h * 64 + nt * 16 + l16] =
          __float2bfloat16(oB[nt][r] * ilb);
    }
  }
}

// ---------------------------------------------------------------------------
extern "C" void kernel_launch(void* const* d_in, const int* in_sizes, int n_in,
                              void* d_out, int out_size, void* d_ws, size_t ws_size,
                              hipStream_t stream)
{
  const float* x  = (const float*)d_in[0];
  const float* Wq = (const float*)d_in[1];
  const float* Wk = (const float*)d_in[2];
  const float* Wv = (const float*)d_in[3];
  const float* Wo = (const float*)d_in[4];
  const float* W1 = (const float*)d_in[5];
  const float* b1 = (const float*)d_in[6];
  const float* W2 = (const float*)d_in[7];
  const float* b2 = (const float*)d_in[8];
  const float* g1 = (const float*)d_in[9];
  const float* g2 = (const float*)d_in[10];

  uint8_t* ws = (uint8_t*)d_ws;
  // 80 MB workspace, lifetimes:
  //  [ 0,  8) WqkvT(6)+WoT(2)      transposes -> QKV gemm / Wo gemm
  //  [ 8, 16) W1T                  -> FFN1
  //  [16, 24) W2T                  -> FFN2
  //  [24, 40) x1 fp32              Wo gemm -> rmsnorm2
  //  [40, 48) xn / Ybuf (shared)   rms1->QKV ; attn->Wo ; rms2->FFN1
  //  [48, 72) QKV                  QKV gemm -> attn
  //  [72, 80) VTg                  transpose_v -> attn
  //  [48, 80) Hbuf (overlay)       FFN1 -> FFN2 (QKV/VTg dead)
  __hip_bfloat16* WqkvT = (__hip_bfloat16*)(ws + 0);
  __hip_bfloat16* WoT   = (__hip_bfloat16*)(ws + 6291456);
  __hip_bfloat16* W1T   = (__hip_bfloat16*)(ws + 8388608);
  __hip_bfloat16* W2T   = (__hip_bfloat16*)(ws + 16777216);
  float*          x1    = (float*)(ws + 25165824);
  __hip_bfloat16* xn    = (__hip_bfloat16*)(ws + 41943040);
  __hip_bfloat16* Ybuf  = (__hip_bfloat16*)(ws + 41943040);  // shares xn slot
  __hip_bfloat16* QKV   = (__hip_bfloat16*)(ws + 50331648);
  __hip_bfloat16* VTg   = (__hip_bfloat16*)(ws + 75497472);
  __hip_bfloat16* Hbuf  = (__hip_bfloat16*)(ws + 50331648);  // overlay QKV+VTg

  const dim3 tb(32, 8);
  transpose_w4<<<dim3(32, 32, 4), tb, 0, stream>>>(Wq, Wk, Wv, Wo, WqkvT);
  transpose_w<<<dim3(128, 32), tb, 0, stream>>>(W1, W1T, 1024, 4096, 1024);
  transpose_w<<<dim3(32, 128), tb, 0, stream>>>(W2, W2T, 4096, 1024, 4096);

  rmsnorm_kernel<<<4096, 256, 0, stream>>>(x, g1, xn, nullptr, nullptr);
  gemm_bt<0, 4><<<dim3(24, 32), 256, 0, stream>>>(xn, WqkvT, nullptr, nullptr, QKV,
                                                  nullptr, 4096, 3072, 1024, 1024);
  transpose_v<<<dim3(64, 64), tb, 0, stream>>>(QKV, VTg);
  attn_kernel<<<512, 256, 0, stream>>>(QKV, VTg, Ybuf);
  gemm_bt<1, 2><<<dim3(8, 64), 256, 0, stream>>>(Ybuf, WoT, nullptr, x, nullptr, x1,
                                                 4096, 1024, 1024, 1024);
  // rmsnorm2 also pre-initializes d_out = x1 + b2 (split-K atomic target)
  rmsnorm_kernel<<<4096, 256, 0, stream>>>(x1, g2, xn, b2, (float*)d_out);
  gemm_bt<2, 4><<<dim3(32, 32), 256, 0, stream>>>(xn, W1T, b1, nullptr, Hbuf, nullptr,
                                                  4096, 4096, 1024, 1024);
  // FFN2 split-K=2: 1024 blocks (4/CU), partials atomicAdd into d_out
  gemm_bt<4, 2><<<dim3(8, 64, 2), 256, 0, stream>>>(Hbuf, W2T, nullptr, nullptr,
                                                    nullptr, (float*)d_out,
                                                    4096, 1024, 4096, 2048);
}

// Round 7
// 344.597 us; speedup vs baseline: 2.2496x; 1.0051x over previous
//
#include <hip/hip_runtime.h>
#include <hip/hip_bf16.h>
#include <math.h>
#include <stdint.h>

// ---------------------------------------------------------------------------
// Transformer block: x + attn(rms(x,g1)) -> x1 ; x1 + ffn(rms(x1,g2))
// B=2 T=2048 D=1024 H=16 Dh=64 FF=4096. All GEMMs bf16 MFMA 16x16x32.
// GEMM K-loop = m97 structure (global_load_lds width-16, 2-barrier).
// R5 lesson: manual VGPR pipelining spills -> keep compiler-friendly loop.
// R6 lesson: occupancy is not the FFN2 limiter; MFMA-per-barrier is ->
//            FFN2 now uses the 128x128 (MT=4) tile + split-K=2.
// LDS tiles use XOR-swizzled 16B chunks (chunk j of row r lives at j^(r&7)).
// ---------------------------------------------------------------------------

typedef __bf16 v8bf  __attribute__((ext_vector_type(8)));
typedef float  v4f   __attribute__((ext_vector_type(4)));

#define T_SEQ 2048
#define EXP2F(x) __builtin_amdgcn_exp2f(x)  // v_exp_f32 (2^x)

// swizzled fragment read: row R, k-elem offset ko (multiple of 8)
#define FRAG(base, R, ko) \
  (*(const v8bf*)((base) + (R) * 64 + (((((ko) >> 3) ^ ((R) & 7))) << 3)))

__device__ __forceinline__ void async_ld16(const void* g, void* l) {
  // global -> LDS direct, 16B/lane. LDS dest is wave-uniform base + lane*16.
  __builtin_amdgcn_global_load_lds(
      (const __attribute__((address_space(1))) uint32_t*)g,
      (__attribute__((address_space(3))) uint32_t*)l, 16, 0, 0);
}

// ---------------- 4x weight transpose (Wq,Wk,Wv,Wo) fused ------------------
// out is contiguous [4][1024][1024] bf16 (WqkvT then WoT).
__global__ __launch_bounds__(256) void transpose_w4(
    const float* __restrict__ Wq, const float* __restrict__ Wk,
    const float* __restrict__ Wv, const float* __restrict__ Wo,
    __hip_bfloat16* __restrict__ out)
{
  __shared__ float tile[32][33];
  const int z = blockIdx.z;
  const float* W = z == 0 ? Wq : z == 1 ? Wk : z == 2 ? Wv : Wo;
  const int n0 = blockIdx.x * 32, k0 = blockIdx.y * 32;
  const int tx = threadIdx.x, ty = threadIdx.y;  // 32 x 8
#pragma unroll
  for (int i = 0; i < 32; i += 8)
    tile[ty + i][tx] = W[(size_t)(k0 + ty + i) * 1024 + n0 + tx];
  __syncthreads();
  __hip_bfloat16* o = out + (size_t)z * 1024 * 1024;
#pragma unroll
  for (int i = 0; i < 32; i += 8)
    o[(size_t)(n0 + ty + i) * 1024 + k0 + tx] = __float2bfloat16(tile[tx][ty + i]);
}

// ---------------- generic weight transpose ----------------------------------
__global__ __launch_bounds__(256) void transpose_w(
    const float* __restrict__ W, __hip_bfloat16* __restrict__ WT,
    int K, int N, int ldo)
{
  __shared__ float tile[32][33];
  const int n0 = blockIdx.x * 32, k0 = blockIdx.y * 32;
  const int tx = threadIdx.x, ty = threadIdx.y;  // 32 x 8
#pragma unroll
  for (int i = 0; i < 32; i += 8)
    tile[ty + i][tx] = W[(size_t)(k0 + ty + i) * N + n0 + tx];
  __syncthreads();
#pragma unroll
  for (int i = 0; i < 32; i += 8)
    WT[(size_t)(n0 + ty + i) * ldo + k0 + tx] = __float2bfloat16(tile[tx][ty + i]);
}

// ---------------- V transpose: QKV V-part -> VTg[b][h][d][t] ---------------
__global__ __launch_bounds__(256) void transpose_v(
    const __hip_bfloat16* __restrict__ QKV, __hip_bfloat16* __restrict__ VTg)
{
  __shared__ float tile[32][33];
  const int t0 = blockIdx.x * 32;
  const int bh = blockIdx.y >> 1;
  const int dt = (blockIdx.y & 1) * 32;
  const int b = bh >> 4, h = bh & 15;
  const int tx = threadIdx.x, ty = threadIdx.y;  // 32 x 8
#pragma unroll
  for (int i = 0; i < 32; i += 8)
    tile[ty + i][tx] = __bfloat162float(
        QKV[(size_t)(b * T_SEQ + t0 + ty + i) * 3072 + 2048 + h * 64 + dt + tx]);
  __syncthreads();
#pragma unroll
  for (int i = 0; i < 32; i += 8)
    VTg[((size_t)bh * 64 + dt + ty + i) * T_SEQ + t0 + tx] =
        __float2bfloat16(tile[tx][ty + i]);
}

// ---------------- RMSNorm (fp32 in -> bf16 out, optional d_out init) -------
// if dinit != nullptr: dinit[row] = x[row] + bias  (pre-initializes the
// split-K atomic target with residual+bias; C partials are atomicAdd'ed).
__global__ __launch_bounds__(256) void rmsnorm_kernel(
    const float* __restrict__ x, const float* __restrict__ g,
    __hip_bfloat16* __restrict__ out,
    const float* __restrict__ bias, float* __restrict__ dinit)
{
  const int row = blockIdx.x;
  const int t = threadIdx.x;
  const float4 v = ((const float4*)(x + (size_t)row * 1024))[t];
  float ss = v.x * v.x + v.y * v.y + v.z * v.z + v.w * v.w;
#pragma unroll
  for (int off = 32; off; off >>= 1) ss += __shfl_xor(ss, off, 64);
  __shared__ float red[4];
  if ((t & 63) == 0) red[t >> 6] = ss;
  __syncthreads();
  ss = red[0] + red[1] + red[2] + red[3];
  const float rs = rsqrtf(ss * (1.0f / 1024.0f) + 1e-6f);
  const float4 gv = ((const float4*)g)[t];
  __hip_bfloat16* o = out + (size_t)row * 1024 + t * 4;
  o[0] = __float2bfloat16(v.x * rs * gv.x);
  o[1] = __float2bfloat16(v.y * rs * gv.y);
  o[2] = __float2bfloat16(v.z * rs * gv.z);
  o[3] = __float2bfloat16(v.w * rs * gv.w);
  if (dinit) {
    const float4 bv = ((const float4*)bias)[t];
    float4 d;
    d.x = v.x + bv.x; d.y = v.y + bv.y; d.z = v.z + bv.z; d.w = v.w + bv.w;
    ((float4*)(dinit + (size_t)row * 1024))[t] = d;
  }
}

// ---------------- GEMM: C = A @ BT^T (+epilogue) ---------------------------
// A [M][K] bf16, BT [N][K] bf16. Tile (32*MT)x128, BK=64, 4 waves 2x2.
// Ksub = K-extent per block (split-K via blockIdx.z; kb = z*Ksub).
// MODE 0: outb = bf16(C)              MODE 1: outf = resid + C
// MODE 2: outb = bf16(gelu(C+bias))   MODE 4: atomicAdd(outf, C)
template <int MODE, int MT>
__global__ __launch_bounds__(256, 2) void gemm_bt(
    const __hip_bfloat16* __restrict__ A,
    const __hip_bfloat16* __restrict__ BT,
    const float* __restrict__ bias,
    const float* __restrict__ resid,
    __hip_bfloat16* __restrict__ outb,
    float* __restrict__ outf,
    int M, int N, int K, int Ksub)
{
  __shared__ __align__(16) __hip_bfloat16 As[32 * MT * 64];
  __shared__ __align__(16) __hip_bfloat16 Bs[128 * 64];
  const int tid = threadIdx.x;
  const int wave = tid >> 6, lane = tid & 63;
  const int quad = lane >> 4, l16 = lane & 15;
  const int m0 = blockIdx.y * (32 * MT), n0 = blockIdx.x * 128;
  const size_t kb = (size_t)blockIdx.z * Ksub;
  const int wr = (wave >> 1) * (16 * MT), wc = (wave & 1) * 64;
  const int lrow = lane >> 3;                 // row within 8-row chunk
  const int scol = ((lane & 7) ^ lrow) * 8;   // swizzled global col fetch

  v4f acc[MT][4];
#pragma unroll
  for (int i = 0; i < MT; i++)
#pragma unroll
    for (int j = 0; j < 4; j++)
#pragma unroll
      for (int c = 0; c < 4; c++) acc[i][j][c] = 0.0f;

  for (int k0 = 0; k0 < Ksub; k0 += 64) {
#pragma unroll
    for (int i = 0; i < MT + 4; i++) {
      const int c = wave * (MT + 4) + i;
      if (c < 4 * MT) {
        async_ld16(A + (size_t)(m0 + c * 8 + lrow) * K + kb + k0 + scol, As + c * 512);
      } else {
        const int cb = c - 4 * MT;
        async_ld16(BT + (size_t)(n0 + cb * 8 + lrow) * K + kb + k0 + scol,
                   Bs + cb * 512);
      }
    }
    __syncthreads();
#pragma unroll
    for (int ks = 0; ks < 64; ks += 32) {
      v8bf af[MT], bf[4];
#pragma unroll
      for (int mt = 0; mt < MT; mt++)
        af[mt] = FRAG(As, wr + mt * 16 + l16, ks + quad * 8);
#pragma unroll
      for (int nt = 0; nt < 4; nt++)
        bf[nt] = FRAG(Bs, wc + nt * 16 + l16, ks + quad * 8);
#pragma unroll
      for (int mt = 0; mt < MT; mt++)
#pragma unroll
        for (int nt = 0; nt < 4; nt++)
          acc[mt][nt] = __builtin_amdgcn_mfma_f32_16x16x32_bf16(
              af[mt], bf[nt], acc[mt][nt], 0, 0, 0);
    }
    __syncthreads();
  }

  // epilogue: C/D layout col=lane&15, row=quad*4+reg
#pragma unroll
  for (int mt = 0; mt < MT; mt++) {
#pragma unroll
    for (int r = 0; r < 4; r++) {
      const int gm = m0 + wr + mt * 16 + quad * 4 + r;
#pragma unroll
      for (int nt = 0; nt < 4; nt++) {
        const int gn = n0 + wc + nt * 16 + l16;
        float v = acc[mt][nt][r];
        if (MODE == 0) {
          outb[(size_t)gm * N + gn] = __float2bfloat16(v);
        } else if (MODE == 1) {
          outf[(size_t)gm * N + gn] = resid[(size_t)gm * N + gn] + v;
        } else if (MODE == 2) {
          v += bias[gn];
          v = 0.5f * v * (1.0f + erff(v * 0.70710678118654752f));
          outb[(size_t)gm * N + gn] = __float2bfloat16(v);
        } else {
          atomicAdd(&outf[(size_t)gm * N + gn], v);
        }
      }
    }
  }
}

// ---------------- flash attention (causal, no-max exp2 softmax) ------------
// One block = q-tile pair (qa=p, qb=31-p) for one (b,h): uniform 33 k-tiles.
__global__ __launch_bounds__(256, 2) void attn_kernel(
    const __hip_bfloat16* __restrict__ QKV,
    const __hip_bfloat16* __restrict__ VTg,
    __hip_bfloat16* __restrict__ Y)
{
  __shared__ __align__(16) __hip_bfloat16 Ks[2 * 64 * 64];  // [buf][krow][d] swz
  __shared__ __align__(16) __hip_bfloat16 Vs[2 * 64 * 64];  // [buf][d][krow] swz
  __shared__ __align__(16) __hip_bfloat16 PsA[64 * 64];     // [qrow][krow] swz
  __shared__ __align__(16) __hip_bfloat16 PsB[64 * 64];

  const int tid = threadIdx.x;
  const int wave = tid >> 6, lane = tid & 63;
  const int quad = lane >> 4, l16 = lane & 15;
  const int blk = blockIdx.x;
  const int p = blk & 15, h = (blk >> 4) & 15, b = blk >> 8;
  const int qa = p, qb = 31 - p, kmax = qb;
  const size_t rowbase = (size_t)b * T_SEQ;
  const size_t vbase = (size_t)(b * 16 + h) * 64;
  const int lrow = lane >> 3, scol = ((lane & 7) ^ (lane >> 3)) * 8;

  const float QSC = 0.125f * 1.44269504f;
  v8bf aqA[2], aqB[2];
#pragma unroll
  for (int ks = 0; ks < 2; ks++) {
    v8bf q = *(const v8bf*)(QKV + (rowbase + qa * 64 + wave * 16 + l16) * 3072 +
                            h * 64 + ks * 32 + quad * 8);
#pragma unroll
    for (int j = 0; j < 8; j++) aqA[ks][j] = (__bf16)((float)q[j] * QSC);
    q = *(const v8bf*)(QKV + (rowbase + qb * 64 + wave * 16 + l16) * 3072 +
                       h * 64 + ks * 32 + quad * 8);
#pragma unroll
    for (int j = 0; j < 8; j++) aqB[ks][j] = (__bf16)((float)q[j] * QSC);
  }

  v4f oA[4], oB[4];
  float lpA[4], lpB[4];
#pragma unroll
  for (int i = 0; i < 4; i++) {
    lpA[i] = 0.0f; lpB[i] = 0.0f;
#pragma unroll
    for (int c = 0; c < 4; c++) { oA[i][c] = 0.0f; oB[i][c] = 0.0f; }
  }

  auto stage = [&](int kt, int buf) {
#pragma unroll
    for (int i = 0; i < 2; i++) {
      const int r8 = i * 32 + wave * 8;
      const int rr = r8 + lrow;
      async_ld16(QKV + (rowbase + kt * 64 + rr) * 3072 + 1024 + h * 64 + scol,
                 Ks + buf * 4096 + r8 * 64);
      async_ld16(VTg + (vbase + rr) * T_SEQ + kt * 64 + scol,
                 Vs + buf * 4096 + r8 * 64);
    }
  };
  stage(0, 0);

  auto softmax_store = [&](v4f s[4], float lp[4], __hip_bfloat16* Ps, bool diag) {
    if (diag) {
#pragma unroll
      for (int nt = 0; nt < 4; nt++) {
        const int colr = nt * 16 + l16;
#pragma unroll
        for (int r = 0; r < 4; r++)
          if (colr > wave * 16 + quad * 4 + r) s[nt][r] = -30000.0f;
      }
    }
#pragma unroll
    for (int r = 0; r < 4; r++) {
      const int row = wave * 16 + quad * 4 + r;
      const int rsw = (quad * 4 + r) & 7;
#pragma unroll
      for (int nt = 0; nt < 4; nt++) {
        const float e = EXP2F(s[nt][r]);
        lp[r] += e;
        const int chunk = (nt * 2 + (l16 >> 3)) ^ rsw;
        Ps[row * 64 + (chunk << 3) + (l16 & 7)] = __float2bfloat16(e);
      }
    }
  };

  for (int kt = 0; kt <= kmax; kt++) {
    __syncthreads();
    if (kt < kmax) stage(kt + 1, (kt + 1) & 1);
    const __hip_bfloat16* Kb = Ks + (kt & 1) * 4096;
    const __hip_bfloat16* Vb = Vs + (kt & 1) * 4096;
    const bool doA = (kt <= qa);

    {
      v8bf kf[2][4];
#pragma unroll
      for (int ks = 0; ks < 2; ks++)
#pragma unroll
        for (int nt = 0; nt < 4; nt++)
          kf[ks][nt] = FRAG(Kb, nt * 16 + l16, ks * 32 + quad * 8);

      v4f sB[4];
#pragma unroll
      for (int nt = 0; nt < 4; nt++)
#pragma unroll
        for (int c = 0; c < 4; c++) sB[nt][c] = 0.0f;
#pragma unroll
      for (int ks = 0; ks < 2; ks++)
#pragma unroll
        for (int nt = 0; nt < 4; nt++)
          sB[nt] = __builtin_amdgcn_mfma_f32_16x16x32_bf16(aqB[ks], kf[ks][nt],
                                                           sB[nt], 0, 0, 0);
      softmax_store(sB, lpB, PsB, kt == qb);

      if (doA) {
        v4f sA[4];
#pragma unroll
        for (int nt = 0; nt < 4; nt++)
#pragma unroll
          for (int c = 0; c < 4; c++) sA[nt][c] = 0.0f;
#pragma unroll
        for (int ks = 0; ks < 2; ks++)
#pragma unroll
          for (int nt = 0; nt < 4; nt++)
            sA[nt] = __builtin_amdgcn_mfma_f32_16x16x32_bf16(aqA[ks], kf[ks][nt],
                                                             sA[nt], 0, 0, 0);
        softmax_store(sA, lpA, PsA, kt == qa);
      }
    }

    {
      v8bf vf[2][4];
#pragma unroll
      for (int ks = 0; ks < 2; ks++)
#pragma unroll
        for (int nt = 0; nt < 4; nt++)
          vf[ks][nt] = FRAG(Vb, nt * 16 + l16, ks * 32 + quad * 8);
#pragma unroll
      for (int ks = 0; ks < 2; ks++) {
        const v8bf apB = FRAG(PsB, wave * 16 + l16, ks * 32 + quad * 8);
#pragma unroll
        for (int nt = 0; nt < 4; nt++)
          oB[nt] = __builtin_amdgcn_mfma_f32_16x16x32_bf16(apB, vf[ks][nt],
                                                           oB[nt], 0, 0, 0);
      }
      if (doA) {
#pragma unroll
        for (int ks = 0; ks < 2; ks++) {
          const v8bf apA = FRAG(PsA, wave * 16 + l16, ks * 32 + quad * 8);
#pragma unroll
          for (int nt = 0; nt < 4; nt++)
            oA[nt] = __builtin_amdgcn_mfma_f32_16x16x32_bf16(apA, vf[ks][nt],
                                                             oA[nt], 0, 0, 0);
        }
      }
    }
  }

#pragma unroll
  for (int r = 0; r < 4; r++) {
    float la = lpA[r], lb = lpB[r];
#pragma unroll
    for (int off = 1; off < 16; off <<= 1) {
      la += __shfl_xor(la, off, 16);
      lb += __shfl_xor(lb, off, 16);
    }
    const float ila = 1.0f / la, ilb = 1.0f / lb;
#pragma unroll
    for (int nt = 0; nt < 4; nt++) {
      Y[(rowbase + qa * 64 + wave * 16 + quad * 4 + r) * 1024 + h * 64 + nt * 16 + l16] =
          __float2bfloat16(oA[nt][r] * ila);
      Y[(rowbase + qb * 64 + wave * 16 + quad * 4 + r) * 1024 + h * 64 + nt * 16 + l16] =
          __float2bfloat16(oB[nt][r] * ilb);
    }
  }
}

// ---------------------------------------------------------------------------
extern "C" void kernel_launch(void* const* d_in, const int* in_sizes, int n_in,
                              void* d_out, int out_size, void* d_ws, size_t ws_size,
                              hipStream_t stream)
{
  const float* x  = (const float*)d_in[0];
  const float* Wq = (const float*)d_in[1];
  const float* Wk = (const float*)d_in[2];
  const float* Wv = (const float*)d_in[3];
  const float* Wo = (const float*)d_in[4];
  const float* W1 = (const float*)d_in[5];
  const float* b1 = (const float*)d_in[6];
  const float* W2 = (const float*)d_in[7];
  const float* b2 = (const float*)d_in[8];
  const float* g1 = (const float*)d_in[9];
  const float* g2 = (const float*)d_in[10];

  uint8_t* ws = (uint8_t*)d_ws;
  // 80 MB workspace, lifetimes:
  //  [ 0,  8) WqkvT(6)+WoT(2)      transposes -> QKV gemm / Wo gemm
  //  [ 8, 16) W1T                  -> FFN1
  //  [16, 24) W2T                  -> FFN2
  //  [24, 40) x1 fp32              Wo gemm -> rmsnorm2
  //  [40, 48) xn / Ybuf (shared)   rms1->QKV ; attn->Wo ; rms2->FFN1
  //  [48, 72) QKV                  QKV gemm -> attn
  //  [72, 80) VTg                  transpose_v -> attn
  //  [48, 80) Hbuf (overlay)       FFN1 -> FFN2 (QKV/VTg dead)
  __hip_bfloat16* WqkvT = (__hip_bfloat16*)(ws + 0);
  __hip_bfloat16* WoT   = (__hip_bfloat16*)(ws + 6291456);
  __hip_bfloat16* W1T   = (__hip_bfloat16*)(ws + 8388608);
  __hip_bfloat16* W2T   = (__hip_bfloat16*)(ws + 16777216);
  float*          x1    = (float*)(ws + 25165824);
  __hip_bfloat16* xn    = (__hip_bfloat16*)(ws + 41943040);
  __hip_bfloat16* Ybuf  = (__hip_bfloat16*)(ws + 41943040);  // shares xn slot
  __hip_bfloat16* QKV   = (__hip_bfloat16*)(ws + 50331648);
  __hip_bfloat16* VTg   = (__hip_bfloat16*)(ws + 75497472);
  __hip_bfloat16* Hbuf  = (__hip_bfloat16*)(ws + 50331648);  // overlay QKV+VTg

  const dim3 tb(32, 8);
  transpose_w4<<<dim3(32, 32, 4), tb, 0, stream>>>(Wq, Wk, Wv, Wo, WqkvT);
  transpose_w<<<dim3(128, 32), tb, 0, stream>>>(W1, W1T, 1024, 4096, 1024);
  transpose_w<<<dim3(32, 128), tb, 0, stream>>>(W2, W2T, 4096, 1024, 4096);

  rmsnorm_kernel<<<4096, 256, 0, stream>>>(x, g1, xn, nullptr, nullptr);
  gemm_bt<0, 4><<<dim3(24, 32), 256, 0, stream>>>(xn, WqkvT, nullptr, nullptr, QKV,
                                                  nullptr, 4096, 3072, 1024, 1024);
  transpose_v<<<dim3(64, 64), tb, 0, stream>>>(QKV, VTg);
  attn_kernel<<<512, 256, 0, stream>>>(QKV, VTg, Ybuf);
  gemm_bt<1, 2><<<dim3(8, 64), 256, 0, stream>>>(Ybuf, WoT, nullptr, x, nullptr, x1,
                                                 4096, 1024, 1024, 1024);
  // rmsnorm2 also pre-initializes d_out = x1 + b2 (split-K atomic target)
  rmsnorm_kernel<<<4096, 256, 0, stream>>>(x1, g2, xn, b2, (float*)d_out);
  gemm_bt<2, 4><<<dim3(32, 32), 256, 0, stream>>>(xn, W1T, b1, nullptr, Hbuf, nullptr,
                                                  4096, 4096, 1024, 1024);
  // FFN2 split-K=2, 128x128 tiles: 512 blocks (2/CU), 32 k-iters each;
  // partials atomicAdd into d_out (pre-initialized with x1 + b2)
  gemm_bt<4, 4><<<dim3(8, 32, 2), 256, 0, stream>>>(Hbuf, W2T, nullptr, nullptr,
                                                    nullptr, (float*)d_out,
                                                    4096, 1024, 4096, 2048);
}

// Round 8
// 328.514 us; speedup vs baseline: 2.3598x; 1.0490x over previous
//
#include <hip/hip_runtime.h>
#include <hip/hip_bf16.h>
#include <math.h>
#include <stdint.h>

// ---------------------------------------------------------------------------
// Transformer block: x + attn(rms(x,g1)) -> x1 ; x1 + ffn(rms(x1,g2))
// B=2 T=2048 D=1024 H=16 Dh=64 FF=4096. All GEMMs bf16 MFMA 16x16x32.
// GEMM K-loop = m97 structure (global_load_lds width-16, 2-barrier).
// R5: manual VGPR pipelining spills -> keep compiler-friendly loop.
// R6/R7: concurrency (4 blocks/CU) beats MFMA-per-barrier -> FFN2 is MT=2.
// R8: XCD-aware block swizzle (id&7 -> 2D patch) so co-XCD blocks share
//     tiles in their local L2; tanh-GELU replaces erff in FFN1 epilogue.
// LDS tiles use XOR-swizzled 16B chunks (chunk j of row r lives at j^(r&7)).
// ---------------------------------------------------------------------------

typedef __bf16 v8bf  __attribute__((ext_vector_type(8)));
typedef float  v4f   __attribute__((ext_vector_type(4)));

#define T_SEQ 2048
#define EXP2F(x) __builtin_amdgcn_exp2f(x)  // v_exp_f32 (2^x)

// swizzled fragment read: row R, k-elem offset ko (multiple of 8)
#define FRAG(base, R, ko) \
  (*(const v8bf*)((base) + (R) * 64 + (((((ko) >> 3) ^ ((R) & 7))) << 3)))

__device__ __forceinline__ void async_ld16(const void* g, void* l) {
  // global -> LDS direct, 16B/lane. LDS dest is wave-uniform base + lane*16.
  __builtin_amdgcn_global_load_lds(
      (const __attribute__((address_space(1))) uint32_t*)g,
      (__attribute__((address_space(3))) uint32_t*)l, 16, 0, 0);
}

// ---------------- 4x weight transpose (Wq,Wk,Wv,Wo) fused ------------------
// out is contiguous [4][1024][1024] bf16 (WqkvT then WoT).
__global__ __launch_bounds__(256) void transpose_w4(
    const float* __restrict__ Wq, const float* __restrict__ Wk,
    const float* __restrict__ Wv, const float* __restrict__ Wo,
    __hip_bfloat16* __restrict__ out)
{
  __shared__ float tile[32][33];
  const int z = blockIdx.z;
  const float* W = z == 0 ? Wq : z == 1 ? Wk : z == 2 ? Wv : Wo;
  const int n0 = blockIdx.x * 32, k0 = blockIdx.y * 32;
  const int tx = threadIdx.x, ty = threadIdx.y;  // 32 x 8
#pragma unroll
  for (int i = 0; i < 32; i += 8)
    tile[ty + i][tx] = W[(size_t)(k0 + ty + i) * 1024 + n0 + tx];
  __syncthreads();
  __hip_bfloat16* o = out + (size_t)z * 1024 * 1024;
#pragma unroll
  for (int i = 0; i < 32; i += 8)
    o[(size_t)(n0 + ty + i) * 1024 + k0 + tx] = __float2bfloat16(tile[tx][ty + i]);
}

// ---------------- generic weight transpose ----------------------------------
__global__ __launch_bounds__(256) void transpose_w(
    const float* __restrict__ W, __hip_bfloat16* __restrict__ WT,
    int K, int N, int ldo)
{
  __shared__ float tile[32][33];
  const int n0 = blockIdx.x * 32, k0 = blockIdx.y * 32;
  const int tx = threadIdx.x, ty = threadIdx.y;  // 32 x 8
#pragma unroll
  for (int i = 0; i < 32; i += 8)
    tile[ty + i][tx] = W[(size_t)(k0 + ty + i) * N + n0 + tx];
  __syncthreads();
#pragma unroll
  for (int i = 0; i < 32; i += 8)
    WT[(size_t)(n0 + ty + i) * ldo + k0 + tx] = __float2bfloat16(tile[tx][ty + i]);
}

// ---------------- V transpose: QKV V-part -> VTg[b][h][d][t] ---------------
__global__ __launch_bounds__(256) void transpose_v(
    const __hip_bfloat16* __restrict__ QKV, __hip_bfloat16* __restrict__ VTg)
{
  __shared__ float tile[32][33];
  const int t0 = blockIdx.x * 32;
  const int bh = blockIdx.y >> 1;
  const int dt = (blockIdx.y & 1) * 32;
  const int b = bh >> 4, h = bh & 15;
  const int tx = threadIdx.x, ty = threadIdx.y;  // 32 x 8
#pragma unroll
  for (int i = 0; i < 32; i += 8)
    tile[ty + i][tx] = __bfloat162float(
        QKV[(size_t)(b * T_SEQ + t0 + ty + i) * 3072 + 2048 + h * 64 + dt + tx]);
  __syncthreads();
#pragma unroll
  for (int i = 0; i < 32; i += 8)
    VTg[((size_t)bh * 64 + dt + ty + i) * T_SEQ + t0 + tx] =
        __float2bfloat16(tile[tx][ty + i]);
}

// ---------------- RMSNorm (fp32 in -> bf16 out, optional d_out init) -------
__global__ __launch_bounds__(256) void rmsnorm_kernel(
    const float* __restrict__ x, const float* __restrict__ g,
    __hip_bfloat16* __restrict__ out,
    const float* __restrict__ bias, float* __restrict__ dinit)
{
  const int row = blockIdx.x;
  const int t = threadIdx.x;
  const float4 v = ((const float4*)(x + (size_t)row * 1024))[t];
  float ss = v.x * v.x + v.y * v.y + v.z * v.z + v.w * v.w;
#pragma unroll
  for (int off = 32; off; off >>= 1) ss += __shfl_xor(ss, off, 64);
  __shared__ float red[4];
  if ((t & 63) == 0) red[t >> 6] = ss;
  __syncthreads();
  ss = red[0] + red[1] + red[2] + red[3];
  const float rs = rsqrtf(ss * (1.0f / 1024.0f) + 1e-6f);
  const float4 gv = ((const float4*)g)[t];
  __hip_bfloat16* o = out + (size_t)row * 1024 + t * 4;
  o[0] = __float2bfloat16(v.x * rs * gv.x);
  o[1] = __float2bfloat16(v.y * rs * gv.y);
  o[2] = __float2bfloat16(v.z * rs * gv.z);
  o[3] = __float2bfloat16(v.w * rs * gv.w);
  if (dinit) {
    const float4 bv = ((const float4*)bias)[t];
    float4 d;
    d.x = v.x + bv.x; d.y = v.y + bv.y; d.z = v.z + bv.z; d.w = v.w + bv.w;
    ((float4*)(dinit + (size_t)row * 1024))[t] = d;
  }
}

// ---------------- GEMM: C = A @ BT^T (+epilogue) ---------------------------
// A [M][K] bf16, BT [N][K] bf16. Tile (32*MT)x128, BK=64, 4 waves 2x2.
// Ksub = K-extent per block (split-K via blockIdx.z; kb = z*Ksub).
// PX*PY=8: XCD swizzle — XCD (id&7) owns a (gridX/PX)x(gridY/PY) tile patch
// so tiles shared by co-XCD blocks live in the local (non-coherent) L2.
// MODE 0: outb = bf16(C)              MODE 1: outf = resid + C
// MODE 2: outb = bf16(gelu(C+bias))   MODE 4: atomicAdd(outf, C)
template <int MODE, int MT, int PX, int PY>
__global__ __launch_bounds__(256, 2) void gemm_bt(
    const __hip_bfloat16* __restrict__ A,
    const __hip_bfloat16* __restrict__ BT,
    const float* __restrict__ bias,
    const float* __restrict__ resid,
    __hip_bfloat16* __restrict__ outb,
    float* __restrict__ outf,
    int M, int N, int K, int Ksub)
{
  __shared__ __align__(16) __hip_bfloat16 As[32 * MT * 64];
  __shared__ __align__(16) __hip_bfloat16 Bs[128 * 64];
  const int tid = threadIdx.x;
  const int wave = tid >> 6, lane = tid & 63;
  const int quad = lane >> 4, l16 = lane & 15;

  // XCD-aware remap: id&7 ~ XCD (empirical round-robin); bijective per z.
  int bx = blockIdx.x, by = blockIdx.y;
  {
    const int id = by * gridDim.x + bx;
    const int k = id & 7, s = id >> 3;
    const int pw = gridDim.x / PX, ph = gridDim.y / PY;
    bx = (k % PX) * pw + (s % pw);
    by = (k / PX) * ph + (s / pw);
  }
  const int m0 = by * (32 * MT), n0 = bx * 128;
  const size_t kb = (size_t)blockIdx.z * Ksub;
  const int wr = (wave >> 1) * (16 * MT), wc = (wave & 1) * 64;
  const int lrow = lane >> 3;                 // row within 8-row chunk
  const int scol = ((lane & 7) ^ lrow) * 8;   // swizzled global col fetch

  v4f acc[MT][4];
#pragma unroll
  for (int i = 0; i < MT; i++)
#pragma unroll
    for (int j = 0; j < 4; j++)
#pragma unroll
      for (int c = 0; c < 4; c++) acc[i][j][c] = 0.0f;

  for (int k0 = 0; k0 < Ksub; k0 += 64) {
#pragma unroll
    for (int i = 0; i < MT + 4; i++) {
      const int c = wave * (MT + 4) + i;
      if (c < 4 * MT) {
        async_ld16(A + (size_t)(m0 + c * 8 + lrow) * K + kb + k0 + scol, As + c * 512);
      } else {
        const int cb = c - 4 * MT;
        async_ld16(BT + (size_t)(n0 + cb * 8 + lrow) * K + kb + k0 + scol,
                   Bs + cb * 512);
      }
    }
    __syncthreads();
#pragma unroll
    for (int ks = 0; ks < 64; ks += 32) {
      v8bf af[MT], bf[4];
#pragma unroll
      for (int mt = 0; mt < MT; mt++)
        af[mt] = FRAG(As, wr + mt * 16 + l16, ks + quad * 8);
#pragma unroll
      for (int nt = 0; nt < 4; nt++)
        bf[nt] = FRAG(Bs, wc + nt * 16 + l16, ks + quad * 8);
#pragma unroll
      for (int mt = 0; mt < MT; mt++)
#pragma unroll
        for (int nt = 0; nt < 4; nt++)
          acc[mt][nt] = __builtin_amdgcn_mfma_f32_16x16x32_bf16(
              af[mt], bf[nt], acc[mt][nt], 0, 0, 0);
    }
    __syncthreads();
  }

  // epilogue: C/D layout col=lane&15, row=quad*4+reg
#pragma unroll
  for (int mt = 0; mt < MT; mt++) {
#pragma unroll
    for (int r = 0; r < 4; r++) {
      const int gm = m0 + wr + mt * 16 + quad * 4 + r;
#pragma unroll
      for (int nt = 0; nt < 4; nt++) {
        const int gn = n0 + wc + nt * 16 + l16;
        float v = acc[mt][nt][r];
        if (MODE == 0) {
          outb[(size_t)gm * N + gn] = __float2bfloat16(v);
        } else if (MODE == 1) {
          outf[(size_t)gm * N + gn] = resid[(size_t)gm * N + gn] + v;
        } else if (MODE == 2) {
          v += bias[gn];
          // tanh-GELU (max |err| ~1e-3 in h -> <1e-3 in final output)
          const float u = 0.7978845608f * (v + 0.044715f * v * v * v);
          const float e = EXP2F(u * 2.885390082f);  // exp(2u)
          const float th = 1.0f - 2.0f * __builtin_amdgcn_rcpf(e + 1.0f);
          v = 0.5f * v * (1.0f + th);
          outb[(size_t)gm * N + gn] = __float2bfloat16(v);
        } else {
          atomicAdd(&outf[(size_t)gm * N + gn], v);
        }
      }
    }
  }
}

// ---------------- flash attention (causal, no-max exp2 softmax) ------------
// One block = q-tile pair (qa=p, qb=31-p) for one (b,h): uniform 33 k-tiles.
__global__ __launch_bounds__(256, 2) void attn_kernel(
    const __hip_bfloat16* __restrict__ QKV,
    const __hip_bfloat16* __restrict__ VTg,
    __hip_bfloat16* __restrict__ Y)
{
  __shared__ __align__(16) __hip_bfloat16 Ks[2 * 64 * 64];  // [buf][krow][d] swz
  __shared__ __align__(16) __hip_bfloat16 Vs[2 * 64 * 64];  // [buf][d][krow] swz
  __shared__ __align__(16) __hip_bfloat16 PsA[64 * 64];     // [qrow][krow] swz
  __shared__ __align__(16) __hip_bfloat16 PsB[64 * 64];

  const int tid = threadIdx.x;
  const int wave = tid >> 6, lane = tid & 63;
  const int quad = lane >> 4, l16 = lane & 15;
  const int blk = blockIdx.x;
  const int p = blk & 15, h = (blk >> 4) & 15, b = blk >> 8;
  const int qa = p, qb = 31 - p, kmax = qb;
  const size_t rowbase = (size_t)b * T_SEQ;
  const size_t vbase = (size_t)(b * 16 + h) * 64;
  const int lrow = lane >> 3, scol = ((lane & 7) ^ (lane >> 3)) * 8;

  const float QSC = 0.125f * 1.44269504f;
  v8bf aqA[2], aqB[2];
#pragma unroll
  for (int ks = 0; ks < 2; ks++) {
    v8bf q = *(const v8bf*)(QKV + (rowbase + qa * 64 + wave * 16 + l16) * 3072 +
                            h * 64 + ks * 32 + quad * 8);
#pragma unroll
    for (int j = 0; j < 8; j++) aqA[ks][j] = (__bf16)((float)q[j] * QSC);
    q = *(const v8bf*)(QKV + (rowbase + qb * 64 + wave * 16 + l16) * 3072 +
                       h * 64 + ks * 32 + quad * 8);
#pragma unroll
    for (int j = 0; j < 8; j++) aqB[ks][j] = (__bf16)((float)q[j] * QSC);
  }

  v4f oA[4], oB[4];
  float lpA[4], lpB[4];
#pragma unroll
  for (int i = 0; i < 4; i++) {
    lpA[i] = 0.0f; lpB[i] = 0.0f;
#pragma unroll
    for (int c = 0; c < 4; c++) { oA[i][c] = 0.0f; oB[i][c] = 0.0f; }
  }

  auto stage = [&](int kt, int buf) {
#pragma unroll
    for (int i = 0; i < 2; i++) {
      const int r8 = i * 32 + wave * 8;
      const int rr = r8 + lrow;
      async_ld16(QKV + (rowbase + kt * 64 + rr) * 3072 + 1024 + h * 64 + scol,
                 Ks + buf * 4096 + r8 * 64);
      async_ld16(VTg + (vbase + rr) * T_SEQ + kt * 64 + scol,
                 Vs + buf * 4096 + r8 * 64);
    }
  };
  stage(0, 0);

  auto softmax_store = [&](v4f s[4], float lp[4], __hip_bfloat16* Ps, bool diag) {
    if (diag) {
#pragma unroll
      for (int nt = 0; nt < 4; nt++) {
        const int colr = nt * 16 + l16;
#pragma unroll
        for (int r = 0; r < 4; r++)
          if (colr > wave * 16 + quad * 4 + r) s[nt][r] = -30000.0f;
      }
    }
#pragma unroll
    for (int r = 0; r < 4; r++) {
      const int row = wave * 16 + quad * 4 + r;
      const int rsw = (quad * 4 + r) & 7;
#pragma unroll
      for (int nt = 0; nt < 4; nt++) {
        const float e = EXP2F(s[nt][r]);
        lp[r] += e;
        const int chunk = (nt * 2 + (l16 >> 3)) ^ rsw;
        Ps[row * 64 + (chunk << 3) + (l16 & 7)] = __float2bfloat16(e);
      }
    }
  };

  for (int kt = 0; kt <= kmax; kt++) {
    __syncthreads();
    if (kt < kmax) stage(kt + 1, (kt + 1) & 1);
    const __hip_bfloat16* Kb = Ks + (kt & 1) * 4096;
    const __hip_bfloat16* Vb = Vs + (kt & 1) * 4096;
    const bool doA = (kt <= qa);

    {
      v8bf kf[2][4];
#pragma unroll
      for (int ks = 0; ks < 2; ks++)
#pragma unroll
        for (int nt = 0; nt < 4; nt++)
          kf[ks][nt] = FRAG(Kb, nt * 16 + l16, ks * 32 + quad * 8);

      v4f sB[4];
#pragma unroll
      for (int nt = 0; nt < 4; nt++)
#pragma unroll
        for (int c = 0; c < 4; c++) sB[nt][c] = 0.0f;
#pragma unroll
      for (int ks = 0; ks < 2; ks++)
#pragma unroll
        for (int nt = 0; nt < 4; nt++)
          sB[nt] = __builtin_amdgcn_mfma_f32_16x16x32_bf16(aqB[ks], kf[ks][nt],
                                                           sB[nt], 0, 0, 0);
      softmax_store(sB, lpB, PsB, kt == qb);

      if (doA) {
        v4f sA[4];
#pragma unroll
        for (int nt = 0; nt < 4; nt++)
#pragma unroll
          for (int c = 0; c < 4; c++) sA[nt][c] = 0.0f;
#pragma unroll
        for (int ks = 0; ks < 2; ks++)
#pragma unroll
          for (int nt = 0; nt < 4; nt++)
            sA[nt] = __builtin_amdgcn_mfma_f32_16x16x32_bf16(aqA[ks], kf[ks][nt],
                                                             sA[nt], 0, 0, 0);
        softmax_store(sA, lpA, PsA, kt == qa);
      }
    }

    {
      v8bf vf[2][4];
#pragma unroll
      for (int ks = 0; ks < 2; ks++)
#pragma unroll
        for (int nt = 0; nt < 4; nt++)
          vf[ks][nt] = FRAG(Vb, nt * 16 + l16, ks * 32 + quad * 8);
#pragma unroll
      for (int ks = 0; ks < 2; ks++) {
        const v8bf apB = FRAG(PsB, wave * 16 + l16, ks * 32 + quad * 8);
#pragma unroll
        for (int nt = 0; nt < 4; nt++)
          oB[nt] = __builtin_amdgcn_mfma_f32_16x16x32_bf16(apB, vf[ks][nt],
                                                           oB[nt], 0, 0, 0);
      }
      if (doA) {
#pragma unroll
        for (int ks = 0; ks < 2; ks++) {
          const v8bf apA = FRAG(PsA, wave * 16 + l16, ks * 32 + quad * 8);
#pragma unroll
          for (int nt = 0; nt < 4; nt++)
            oA[nt] = __builtin_amdgcn_mfma_f32_16x16x32_bf16(apA, vf[ks][nt],
                                                             oA[nt], 0, 0, 0);
        }
      }
    }
  }

#pragma unroll
  for (int r = 0; r < 4; r++) {
    float la = lpA[r], lb = lpB[r];
#pragma unroll
    for (int off = 1; off < 16; off <<= 1) {
      la += __shfl_xor(la, off, 16);
      lb += __shfl_xor(lb, off, 16);
    }
    const float ila = 1.0f / la, ilb = 1.0f / lb;
#pragma unroll
    for (int nt = 0; nt < 4; nt++) {
      Y[(rowbase + qa * 64 + wave * 16 + quad * 4 + r) * 1024 + h * 64 + nt * 16 + l16] =
          __float2bfloat16(oA[nt][r] * ila);
      Y[(rowbase + qb * 64 + wave * 16 + quad * 4 + r) * 1024 + h * 64 + nt * 16 + l16] =
          __float2bfloat16(oB[nt][r] * ilb);
    }
  }
}

// ---------------------------------------------------------------------------
extern "C" void kernel_launch(void* const* d_in, const int* in_sizes, int n_in,
                              void* d_out, int out_size, void* d_ws, size_t ws_size,
                              hipStream_t stream)
{
  const float* x  = (const float*)d_in[0];
  const float* Wq = (const float*)d_in[1];
  const float* Wk = (const float*)d_in[2];
  const float* Wv = (const float*)d_in[3];
  const float* Wo = (const float*)d_in[4];
  const float* W1 = (const float*)d_in[5];
  const float* b1 = (const float*)d_in[6];
  const float* W2 = (const float*)d_in[7];
  const float* b2 = (const float*)d_in[8];
  const float* g1 = (const float*)d_in[9];
  const float* g2 = (const float*)d_in[10];

  uint8_t* ws = (uint8_t*)d_ws;
  // 80 MB workspace, lifetimes:
  //  [ 0,  8) WqkvT(6)+WoT(2)      transposes -> QKV gemm / Wo gemm
  //  [ 8, 16) W1T                  -> FFN1
  //  [16, 24) W2T                  -> FFN2
  //  [24, 40) x1 fp32              Wo gemm -> rmsnorm2
  //  [40, 48) xn / Ybuf (shared)   rms1->QKV ; attn->Wo ; rms2->FFN1
  //  [48, 72) QKV                  QKV gemm -> attn
  //  [72, 80) VTg                  transpose_v -> attn
  //  [48, 80) Hbuf (overlay)       FFN1 -> FFN2 (QKV/VTg dead)
  __hip_bfloat16* WqkvT = (__hip_bfloat16*)(ws + 0);
  __hip_bfloat16* WoT   = (__hip_bfloat16*)(ws + 6291456);
  __hip_bfloat16* W1T   = (__hip_bfloat16*)(ws + 8388608);
  __hip_bfloat16* W2T   = (__hip_bfloat16*)(ws + 16777216);
  float*          x1    = (float*)(ws + 25165824);
  __hip_bfloat16* xn    = (__hip_bfloat16*)(ws + 41943040);
  __hip_bfloat16* Ybuf  = (__hip_bfloat16*)(ws + 41943040);  // shares xn slot
  __hip_bfloat16* QKV   = (__hip_bfloat16*)(ws + 50331648);
  __hip_bfloat16* VTg   = (__hip_bfloat16*)(ws + 75497472);
  __hip_bfloat16* Hbuf  = (__hip_bfloat16*)(ws + 50331648);  // overlay QKV+VTg

  const dim3 tb(32, 8);
  transpose_w4<<<dim3(32, 32, 4), tb, 0, stream>>>(Wq, Wk, Wv, Wo, WqkvT);
  transpose_w<<<dim3(128, 32), tb, 0, stream>>>(W1, W1T, 1024, 4096, 1024);
  transpose_w<<<dim3(32, 128), tb, 0, stream>>>(W2, W2T, 4096, 1024, 4096);

  rmsnorm_kernel<<<4096, 256, 0, stream>>>(x, g1, xn, nullptr, nullptr);
  // QKV: grid (24,32) -> XCD patches 6x16
  gemm_bt<0, 4, 4, 2><<<dim3(24, 32), 256, 0, stream>>>(
      xn, WqkvT, nullptr, nullptr, QKV, nullptr, 4096, 3072, 1024, 1024);
  transpose_v<<<dim3(64, 64), tb, 0, stream>>>(QKV, VTg);
  attn_kernel<<<512, 256, 0, stream>>>(QKV, VTg, Ybuf);
  // Wo: grid (8,64) -> XCD owns 8x8 y-band (shares Ybuf rows in-XCD)
  gemm_bt<1, 2, 1, 8><<<dim3(8, 64), 256, 0, stream>>>(
      Ybuf, WoT, nullptr, x, nullptr, x1, 4096, 1024, 1024, 1024);
  // rmsnorm2 also pre-initializes d_out = x1 + b2 (split-K atomic target)
  rmsnorm_kernel<<<4096, 256, 0, stream>>>(x1, g2, xn, b2, (float*)d_out);
  // FFN1: grid (32,32) -> XCD patches 8x16
  gemm_bt<2, 4, 4, 2><<<dim3(32, 32), 256, 0, stream>>>(
      xn, W1T, b1, nullptr, Hbuf, nullptr, 4096, 4096, 1024, 1024);
  // FFN2 split-K=2, MT=2 (R6 best): 1024 blocks (4/CU); XCD owns 8x8 y-band
  // per z (shares Hbuf rows in-XCD); partials atomicAdd into d_out
  gemm_bt<4, 2, 1, 8><<<dim3(8, 64, 2), 256, 0, stream>>>(
      Hbuf, W2T, nullptr, nullptr, nullptr, (float*)d_out, 4096, 1024, 4096, 2048);
}